// Round 1
// baseline (505.202 us; speedup 1.0000x reference)
//
#include <hip/hip_runtime.h>
#include <stdint.h>

#define TSIZE   (1u<<19)
#define P2c 2654435761u
#define P3c 805459861u

#define NTHR 512
#define BM 256

// LDS layout (bytes)
#define H_OFF   0u         // 256 rows x 256B activation buffer (fp16, swizzled)
#define W1_OFF  65536u     // 128 x 64B
#define W2_OFF  73728u     // 128 x 256B
#define W3_OFF  106496u    // 128 x 256B
#define W4_OFF  139264u    // 16 x 256B (rows 2..15 unused garbage, never stored)
#define B_OFF   143360u    // biases f32: b1[128] b2[128] b3[128] b4[2]
#define LDS_BYTES 144960u

typedef _Float16 v8h __attribute__((ext_vector_type(8)));
typedef float    v4f __attribute__((ext_vector_type(4)));

__device__ __forceinline__ uint32_t swz256(uint32_t row, uint32_t off){ return row*256u + (off ^ ((row&7u)<<4)); }
__device__ __forceinline__ uint32_t swz64 (uint32_t row, uint32_t off){ return row*64u  + (off ^ ((row&3u)<<4)); }

template<int K, int O, bool RELU>
__device__ __forceinline__ void mlp_layer(char* sm, uint32_t w_off, const float* bias, int wrow0, int lane)
{
  const int r = lane & 15;
  const int q = lane >> 4;
  v4f acc[2][O/16];
  #pragma unroll
  for (int rt=0;rt<2;rt++)
    #pragma unroll
    for (int ct=0;ct<O/16;ct++){ v4f z = {0.f,0.f,0.f,0.f}; acc[rt][ct] = z; }

  #pragma unroll
  for (int ks=0; ks<K/32; ks++){
    uint32_t abyte = (uint32_t)(ks*64 + q*16);
    v8h a0 = *(const v8h*)(sm + H_OFF + swz256((uint32_t)(wrow0 + r),      abyte));
    v8h a1 = *(const v8h*)(sm + H_OFF + swz256((uint32_t)(wrow0 + 16 + r), abyte));
    #pragma unroll
    for (int ct=0; ct<O/16; ct++){
      uint32_t wrow = (uint32_t)(ct*16 + r);
      v8h b;
      if (K == 32) b = *(const v8h*)(sm + w_off + swz64 (wrow, abyte));
      else         b = *(const v8h*)(sm + w_off + swz256(wrow, abyte));
      acc[0][ct] = __builtin_amdgcn_mfma_f32_16x16x32_f16(a0, b, acc[0][ct], 0,0,0);
      acc[1][ct] = __builtin_amdgcn_mfma_f32_16x16x32_f16(a1, b, acc[1][ct], 0,0,0);
    }
  }
  // epilogue: bias + relu + write back in place (each wave touches only its own rows)
  #pragma unroll
  for (int rt=0;rt<2;rt++){
    #pragma unroll
    for (int ct=0; ct<O/16; ct++){
      float bv = bias[ct*16 + r];
      #pragma unroll
      for (int j=0;j<4;j++){
        float v = acc[rt][ct][j] + bv;
        if (RELU) v = v > 0.f ? v : 0.f;
        uint32_t row = (uint32_t)(wrow0 + rt*16 + q*4 + j);
        *(_Float16*)(sm + H_OFF + swz256(row, (uint32_t)((ct*16 + r)*2))) = (_Float16)v;
      }
    }
  }
}

__global__ __launch_bounds__(NTHR, 2)
void ngp_fused(const float* __restrict__ x,
               const float* __restrict__ table,
               const float* __restrict__ W1, const float* __restrict__ b1,
               const float* __restrict__ W2, const float* __restrict__ b2,
               const float* __restrict__ W3, const float* __restrict__ b3,
               const float* __restrict__ W4, const float* __restrict__ b4,
               float* __restrict__ out, int N)
{
  extern __shared__ char sm[];
  const int tid  = (int)threadIdx.x;
  const int lane = tid & 63;
  const int wave = tid >> 6;

  // ---- stage weights to LDS as fp16 (swizzled) ----
  for (int i = tid; i < 128*32; i += NTHR){
    uint32_t o = (uint32_t)(i >> 5), k = (uint32_t)(i & 31);
    *(_Float16*)(sm + W1_OFF + swz64(o, k*2u)) = (_Float16)W1[i];
  }
  for (int i = tid; i < 128*128; i += NTHR){
    uint32_t o = (uint32_t)(i >> 7), k = (uint32_t)(i & 127);
    *(_Float16*)(sm + W2_OFF + swz256(o, k*2u)) = (_Float16)W2[i];
    *(_Float16*)(sm + W3_OFF + swz256(o, k*2u)) = (_Float16)W3[i];
  }
  for (int i = tid; i < 2*128; i += NTHR){
    uint32_t o = (uint32_t)(i >> 7), k = (uint32_t)(i & 127);
    *(_Float16*)(sm + W4_OFF + swz256(o, k*2u)) = (_Float16)W4[i];
  }
  {
    float* bl = (float*)(sm + B_OFF);
    for (int i = tid; i < 128; i += NTHR){ bl[i] = b1[i]; bl[128+i] = b2[i]; bl[256+i] = b3[i]; }
    if (tid < 2) bl[384+tid] = b4[tid];
  }

  const int ntiles = (N + BM - 1) / BM;
  for (int tile = (int)blockIdx.x; tile < ntiles; tile += (int)gridDim.x){
    const int r0 = tile * BM;
    __syncthreads();   // weights ready (iter 0) / previous iter y-readout done

    // ---- hash-grid encode: task = (row, level), 4 tasks/thread ----
    #pragma unroll
    for (int t=0;t<4;t++){
      int task = t*NTHR + tid;          // 0..2047
      int row  = task >> 3;
      int lev  = task & 7;
      int grow = r0 + row;
      if (grow < N){
        float px = x[grow*6+0], py = x[grow*6+1], pz = x[grow*6+2];
        float res = (float)(16 << lev);
        px *= res; py *= res; pz *= res;
        float fx = floorf(px), fy = floorf(py), fz = floorf(pz);
        float rx = px-fx, ry = py-fy, rz = pz-fz;
        uint32_t ix=(uint32_t)fx, iy=(uint32_t)fy, iz=(uint32_t)fz;
        uint32_t hx0=ix,      hx1=ix+1u;
        uint32_t hy0=iy*P2c,  hy1=(iy+1u)*P2c;
        uint32_t hz0=iz*P3c,  hz1=(iz+1u)*P3c;
        const float2* tbl = (const float2*)table + (size_t)lev*TSIZE;
        const uint32_t m = TSIZE-1u;
        float2 f0 = tbl[(hx0^hy0^hz0)&m];
        float2 f1 = tbl[(hx1^hy0^hz0)&m];
        float2 f2 = tbl[(hx0^hy1^hz0)&m];
        float2 f3 = tbl[(hx1^hy1^hz0)&m];
        float2 f4 = tbl[(hx0^hy0^hz1)&m];
        float2 f5 = tbl[(hx1^hy0^hz1)&m];
        float2 f6 = tbl[(hx0^hy1^hz1)&m];
        float2 f7 = tbl[(hx1^hy1^hz1)&m];
        float wx0=1.f-rx, wy0=1.f-ry, wz0=1.f-rz;
        float w0=wx0*wy0*wz0, w1=rx*wy0*wz0, w2=wx0*ry*wz0, w3=rx*ry*wz0;
        float w4=wx0*wy0*rz,  w5=rx*wy0*rz,  w6=wx0*ry*rz,  w7=rx*ry*rz;
        float s0 = f0.x*w0+f1.x*w1+f2.x*w2+f3.x*w3+f4.x*w4+f5.x*w5+f6.x*w6+f7.x*w7;
        float s1 = f0.y*w0+f1.y*w1+f2.y*w2+f3.y*w3+f4.y*w4+f5.y*w5+f6.y*w6+f7.y*w7;
        union { _Float16 h[2]; uint32_t u; } p;
        p.h[0]=(_Float16)s0; p.h[1]=(_Float16)s1;
        *(uint32_t*)(sm + H_OFF + swz256((uint32_t)row, (uint32_t)(lev*4))) = p.u;
      }
    }
    // ---- SH degree-4 encode: one thread per row (waves 4..7 idle here) ----
    if (tid < BM){
      int row = tid, grow = r0 + row;
      if (grow < N){
        float dx = 2.f*x[grow*6+3]-1.f, dy = 2.f*x[grow*6+4]-1.f, dz = 2.f*x[grow*6+5]-1.f;
        float x2=dx*dx, y2=dy*dy, z2=dz*dz;
        float xy=dx*dy, yz=dy*dz, xz=dx*dz;
        float sh[16];
        sh[0]=0.28209479177387814f;
        sh[1]=-0.48860251190291987f*dy;
        sh[2]= 0.48860251190291987f*dz;
        sh[3]=-0.48860251190291987f*dx;
        sh[4]= 1.0925484305920792f*xy;
        sh[5]=-1.0925484305920792f*yz;
        sh[6]= 0.94617469575756f*z2-0.31539156525252f;
        sh[7]=-1.0925484305920792f*xz;
        sh[8]= 0.5462742152960396f*(x2-y2);
        sh[9]= 0.5900435899266435f*dy*(-3.f*x2+y2);
        sh[10]=2.890611442640554f*xy*dz;
        sh[11]=0.4570457994644657f*dy*(1.f-5.f*z2);
        sh[12]=0.3731763325901154f*dz*(5.f*z2-3.f);
        sh[13]=0.4570457994644657f*dx*(1.f-5.f*z2);
        sh[14]=1.445305721320277f*dz*(x2-y2);
        sh[15]=0.5900435899266435f*dx*(-x2+3.f*y2);
        #pragma unroll
        for (int j=0;j<8;j++){
          union { _Float16 h[2]; uint32_t u; } p;
          p.h[0]=(_Float16)sh[2*j]; p.h[1]=(_Float16)sh[2*j+1];
          *(uint32_t*)(sm + H_OFF + swz256((uint32_t)row, (uint32_t)(32 + 4*j))) = p.u;
        }
      }
    }
    __syncthreads();

    // ---- MLP: each wave owns rows [wave*32, wave*32+32) — no barriers inside ----
    const int wrow0 = wave * 32;
    const float* bl = (const float*)(sm + B_OFF);
    mlp_layer<32, 128, true >(sm, W1_OFF, bl,       wrow0, lane);
    mlp_layer<128,128, true >(sm, W2_OFF, bl + 128, wrow0, lane);
    mlp_layer<128,128, true >(sm, W3_OFF, bl + 256, wrow0, lane);
    // layer 4: K=128, O=16 (cols 0,1 valid)
    {
      const int r = lane & 15, q = lane >> 4;
      v4f acc0 = {0.f,0.f,0.f,0.f}, acc1 = {0.f,0.f,0.f,0.f};
      #pragma unroll
      for (int ks=0; ks<4; ks++){
        uint32_t abyte = (uint32_t)(ks*64 + q*16);
        v8h a0 = *(const v8h*)(sm + H_OFF + swz256((uint32_t)(wrow0 + r),      abyte));
        v8h a1 = *(const v8h*)(sm + H_OFF + swz256((uint32_t)(wrow0 + 16 + r), abyte));
        v8h b  = *(const v8h*)(sm + W4_OFF + swz256((uint32_t)r, abyte));
        acc0 = __builtin_amdgcn_mfma_f32_16x16x32_f16(a0, b, acc0, 0,0,0);
        acc1 = __builtin_amdgcn_mfma_f32_16x16x32_f16(a1, b, acc1, 0,0,0);
      }
      if (r < 2){
        float bv = bl[384 + r];
        #pragma unroll
        for (int j=0;j<4;j++){
          uint32_t row0 = (uint32_t)(wrow0 + q*4 + j);
          *(float*)(sm + H_OFF + swz256(row0,       (uint32_t)(r*4))) = acc0[j] + bv;
          *(float*)(sm + H_OFF + swz256(row0 + 16u, (uint32_t)(r*4))) = acc1[j] + bv;
        }
      }
    }
    __syncthreads();

    // ---- coalesced y readout: 512 threads = 256 rows x 2 cols ----
    {
      int row = tid >> 1, col = tid & 1;
      int grow = r0 + row;
      if (grow < N){
        out[grow*2 + col] = *(const float*)(sm + H_OFF + swz256((uint32_t)row, (uint32_t)(col*4)));
      }
    }
  }
}

extern "C" void kernel_launch(void* const* d_in, const int* in_sizes, int n_in,
                              void* d_out, int out_size, void* d_ws, size_t ws_size,
                              hipStream_t stream)
{
  const float* x  = (const float*)d_in[0];
  const float* tb = (const float*)d_in[1];
  const float* W1 = (const float*)d_in[2];
  const float* b1 = (const float*)d_in[3];
  const float* W2 = (const float*)d_in[4];
  const float* b2 = (const float*)d_in[5];
  const float* W3 = (const float*)d_in[6];
  const float* b3 = (const float*)d_in[7];
  const float* W4 = (const float*)d_in[8];
  const float* b4 = (const float*)d_in[9];
  float* out = (float*)d_out;
  const int N = in_sizes[0] / 6;

  (void)hipFuncSetAttribute((const void*)ngp_fused,
                            hipFuncAttributeMaxDynamicSharedMemorySize, (int)LDS_BYTES);

  const int ntiles = (N + BM - 1) / BM;
  const int grid = ntiles < 1024 ? ntiles : 1024;
  ngp_fused<<<grid, NTHR, LDS_BYTES, stream>>>(x, tb, W1, b1, W2, b2, W3, b3, W4, b4, out, N);
}

// Round 2
// 420.587 us; speedup vs baseline: 1.2012x; 1.2012x over previous
//
#include <hip/hip_runtime.h>
#include <stdint.h>

#define TSIZE   (1u<<19)
#define P2c 2654435761u
#define P3c 805459861u

#define NTHR 512          // fused fallback block
#define NT2  256          // mlp kernel block (4 waves x 64 rows)
#define BM 256

// LDS layout (bytes) — shared by fused fallback and mlp kernel
#define H_OFF   0u         // 256 rows x 256B activation buffer (fp16, swizzled)
#define W1_OFF  65536u     // 128 x 64B
#define W2_OFF  73728u     // 128 x 256B
#define W3_OFF  106496u    // 128 x 256B
#define W4_OFF  139264u    // 16 x 256B (rows 2..15 unused garbage, never stored)
#define B_OFF   143360u    // biases f32: b1[128] b2[128] b3[128] b4[2]
#define LDS_BYTES 144960u

typedef _Float16 v8h __attribute__((ext_vector_type(8)));
typedef _Float16 v4h __attribute__((ext_vector_type(4)));
typedef float    v4f __attribute__((ext_vector_type(4)));

__device__ __forceinline__ uint32_t swz256(uint32_t row, uint32_t off){ return row*256u + (off ^ ((row&7u)<<4)); }
__device__ __forceinline__ uint32_t swz64 (uint32_t row, uint32_t off){ return row*64u  + (off ^ ((row&3u)<<4)); }

template<int K, int O, int RT, bool RELU>
__device__ __forceinline__ void mlp_layer(char* sm, uint32_t w_off, const float* bias, int wrow0, int lane)
{
  const int r = lane & 15;
  const int q = lane >> 4;
  v4f acc[RT][O/16];
  #pragma unroll
  for (int rt=0;rt<RT;rt++)
    #pragma unroll
    for (int ct=0;ct<O/16;ct++){ v4f z = {0.f,0.f,0.f,0.f}; acc[rt][ct] = z; }

  #pragma unroll
  for (int ks=0; ks<K/32; ks++){
    uint32_t abyte = (uint32_t)(ks*64 + q*16);
    v8h a[RT];
    #pragma unroll
    for (int rt=0;rt<RT;rt++)
      a[rt] = *(const v8h*)(sm + H_OFF + swz256((uint32_t)(wrow0 + rt*16 + r), abyte));
    #pragma unroll
    for (int ct=0; ct<O/16; ct++){
      uint32_t wrow = (uint32_t)(ct*16 + r);
      v8h b;
      if (K == 32) b = *(const v8h*)(sm + w_off + swz64 (wrow, abyte));
      else         b = *(const v8h*)(sm + w_off + swz256(wrow, abyte));
      #pragma unroll
      for (int rt=0;rt<RT;rt++)
        acc[rt][ct] = __builtin_amdgcn_mfma_f32_16x16x32_f16(a[rt], b, acc[rt][ct], 0,0,0);
    }
  }
  #pragma unroll
  for (int rt=0;rt<RT;rt++){
    #pragma unroll
    for (int ct=0; ct<O/16; ct++){
      float bv = bias[ct*16 + r];
      #pragma unroll
      for (int j=0;j<4;j++){
        float v = acc[rt][ct][j] + bv;
        if (RELU) v = v > 0.f ? v : 0.f;
        uint32_t row = (uint32_t)(wrow0 + rt*16 + q*4 + j);
        *(_Float16*)(sm + H_OFF + swz256(row, (uint32_t)((ct*16 + r)*2))) = (_Float16)v;
      }
    }
  }
}

__device__ __forceinline__ void sh_to_lds(char* sm, const float* __restrict__ x, int grow, uint32_t row)
{
  float dx = 2.f*x[grow*6+3]-1.f, dy = 2.f*x[grow*6+4]-1.f, dz = 2.f*x[grow*6+5]-1.f;
  float x2=dx*dx, y2=dy*dy, z2=dz*dz;
  float xy=dx*dy, yz=dy*dz, xz=dx*dz;
  float sh[16];
  sh[0]=0.28209479177387814f;
  sh[1]=-0.48860251190291987f*dy;
  sh[2]= 0.48860251190291987f*dz;
  sh[3]=-0.48860251190291987f*dx;
  sh[4]= 1.0925484305920792f*xy;
  sh[5]=-1.0925484305920792f*yz;
  sh[6]= 0.94617469575756f*z2-0.31539156525252f;
  sh[7]=-1.0925484305920792f*xz;
  sh[8]= 0.5462742152960396f*(x2-y2);
  sh[9]= 0.5900435899266435f*dy*(-3.f*x2+y2);
  sh[10]=2.890611442640554f*xy*dz;
  sh[11]=0.4570457994644657f*dy*(1.f-5.f*z2);
  sh[12]=0.3731763325901154f*dz*(5.f*z2-3.f);
  sh[13]=0.4570457994644657f*dx*(1.f-5.f*z2);
  sh[14]=1.445305721320277f*dz*(x2-y2);
  sh[15]=0.5900435899266435f*dx*(-x2+3.f*y2);
  #pragma unroll
  for (int j=0;j<8;j++){
    union { _Float16 h[2]; uint32_t u; } p;
    p.h[0]=(_Float16)sh[2*j]; p.h[1]=(_Float16)sh[2*j+1];
    *(uint32_t*)(sm + H_OFF + swz256(row, (uint32_t)(32 + 4*j))) = p.u;
  }
}

// ============================ kernel 0: table f32 -> fp16 ============================
__global__ __launch_bounds__(256)
void cvt_table(const float* __restrict__ t, _Float16* __restrict__ o, int n4)
{
  int i = (int)(blockIdx.x*blockDim.x + threadIdx.x);
  int stride = (int)(gridDim.x*blockDim.x);
  for (; i < n4; i += stride){
    float4 v = ((const float4*)t)[i];
    v4h h; h[0]=(_Float16)v.x; h[1]=(_Float16)v.y; h[2]=(_Float16)v.z; h[3]=(_Float16)v.w;
    ((v4h*)o)[i] = h;
  }
}

// ============================ kernel 1: hash-grid encode ============================
// one level per block (level = blockIdx & 7 -> pins level to one XCD's L2)
__global__ __launch_bounds__(256)
void encode(const float* __restrict__ x, const _Float16* __restrict__ tb,
            uint32_t* __restrict__ planes, int N)
{
  const int lev = (int)(blockIdx.x & 7u);
  const int nch = (N + 255) >> 8;
  const uint32_t* lvl = (const uint32_t*)(tb + (size_t)lev*TSIZE*2u);
  const float res = (float)(16 << lev);
  const uint32_t m = TSIZE-1u;
  uint32_t* plane = planes + (size_t)lev*(size_t)N;
  for (int c = (int)(blockIdx.x >> 3); c < nch; c += (int)(gridDim.x >> 3)){
    int row = c*256 + (int)threadIdx.x;
    if (row < N){
      float px = x[row*6+0]*res, py = x[row*6+1]*res, pz = x[row*6+2]*res;
      float fx = floorf(px), fy = floorf(py), fz = floorf(pz);
      float rx = px-fx, ry = py-fy, rz = pz-fz;
      uint32_t ix=(uint32_t)fx, iy=(uint32_t)fy, iz=(uint32_t)fz;
      uint32_t hx0=ix,      hx1=ix+1u;
      uint32_t hy0=iy*P2c,  hy1=(iy+1u)*P2c;
      uint32_t hz0=iz*P3c,  hz1=(iz+1u)*P3c;
      uint32_t u0 = lvl[(hx0^hy0^hz0)&m];
      uint32_t u1 = lvl[(hx1^hy0^hz0)&m];
      uint32_t u2 = lvl[(hx0^hy1^hz0)&m];
      uint32_t u3 = lvl[(hx1^hy1^hz0)&m];
      uint32_t u4 = lvl[(hx0^hy0^hz1)&m];
      uint32_t u5 = lvl[(hx1^hy0^hz1)&m];
      uint32_t u6 = lvl[(hx0^hy1^hz1)&m];
      uint32_t u7 = lvl[(hx1^hy1^hz1)&m];
      float wx0=1.f-rx, wy0=1.f-ry, wz0=1.f-rz;
      float w0=wx0*wy0*wz0, w1=rx*wy0*wz0, w2=wx0*ry*wz0, w3=rx*ry*wz0;
      float w4=wx0*wy0*rz,  w5=rx*wy0*rz,  w6=wx0*ry*rz,  w7=rx*ry*rz;
      union { uint32_t u; _Float16 h[2]; } c0,c1,c2,c3,c4,c5,c6,c7;
      c0.u=u0; c1.u=u1; c2.u=u2; c3.u=u3; c4.u=u4; c5.u=u5; c6.u=u6; c7.u=u7;
      float s0 = (float)c0.h[0]*w0+(float)c1.h[0]*w1+(float)c2.h[0]*w2+(float)c3.h[0]*w3
               + (float)c4.h[0]*w4+(float)c5.h[0]*w5+(float)c6.h[0]*w6+(float)c7.h[0]*w7;
      float s1 = (float)c0.h[1]*w0+(float)c1.h[1]*w1+(float)c2.h[1]*w2+(float)c3.h[1]*w3
               + (float)c4.h[1]*w4+(float)c5.h[1]*w5+(float)c6.h[1]*w6+(float)c7.h[1]*w7;
      union { _Float16 h[2]; uint32_t u; } p;
      p.h[0]=(_Float16)s0; p.h[1]=(_Float16)s1;
      plane[row] = p.u;
    }
  }
}

// ============================ kernel 2: MLP (4 waves x 64 rows) ============================
__global__ __launch_bounds__(NT2, 1)
void mlp_kernel(const float* __restrict__ x, const uint32_t* __restrict__ planes,
                const float* __restrict__ W1, const float* __restrict__ b1,
                const float* __restrict__ W2, const float* __restrict__ b2,
                const float* __restrict__ W3, const float* __restrict__ b3,
                const float* __restrict__ W4, const float* __restrict__ b4,
                float* __restrict__ out, int N)
{
  extern __shared__ char sm[];
  const int tid  = (int)threadIdx.x;
  const int lane = tid & 63;
  const int wave = tid >> 6;     // 0..3

  for (int i = tid; i < 128*32; i += NT2){
    uint32_t o = (uint32_t)(i >> 5), k = (uint32_t)(i & 31);
    *(_Float16*)(sm + W1_OFF + swz64(o, k*2u)) = (_Float16)W1[i];
  }
  for (int i = tid; i < 128*128; i += NT2){
    uint32_t o = (uint32_t)(i >> 7), k = (uint32_t)(i & 127);
    *(_Float16*)(sm + W2_OFF + swz256(o, k*2u)) = (_Float16)W2[i];
    *(_Float16*)(sm + W3_OFF + swz256(o, k*2u)) = (_Float16)W3[i];
  }
  for (int i = tid; i < 2*128; i += NT2){
    uint32_t o = (uint32_t)(i >> 7), k = (uint32_t)(i & 127);
    *(_Float16*)(sm + W4_OFF + swz256(o, k*2u)) = (_Float16)W4[i];
  }
  {
    float* bl = (float*)(sm + B_OFF);
    for (int i = tid; i < 128; i += NT2){ bl[i] = b1[i]; bl[128+i] = b2[i]; bl[256+i] = b3[i]; }
    if (tid < 2) bl[384+tid] = b4[tid];
  }

  const int ntiles = (N + BM - 1) / BM;
  for (int tile = (int)blockIdx.x; tile < ntiles; tile += (int)gridDim.x){
    const int r0 = tile * BM;
    __syncthreads();   // weights ready (iter 0) / previous iter readout done

    // hash features from planes (coalesced 4B loads, one level at a time)
    {
      int grow = r0 + tid;
      #pragma unroll
      for (int lv=0; lv<8; lv++){
        uint32_t u = (grow < N) ? planes[(size_t)lv*(size_t)N + grow] : 0u;
        *(uint32_t*)(sm + H_OFF + swz256((uint32_t)tid, (uint32_t)(lv*4))) = u;
      }
      // SH features computed in-kernel
      if (grow < N) sh_to_lds(sm, x, grow, (uint32_t)tid);
    }
    __syncthreads();

    const int wrow0 = wave * 64;
    const float* bl = (const float*)(sm + B_OFF);
    mlp_layer<32, 128, 4, true>(sm, W1_OFF, bl,       wrow0, lane);
    mlp_layer<128,128, 4, true>(sm, W2_OFF, bl + 128, wrow0, lane);
    mlp_layer<128,128, 4, true>(sm, W3_OFF, bl + 256, wrow0, lane);
    // layer 4: K=128, O=16 (cols 0,1 valid)
    {
      const int r = lane & 15, q = lane >> 4;
      v4f acc4[4];
      #pragma unroll
      for (int rt=0;rt<4;rt++){ v4f z = {0.f,0.f,0.f,0.f}; acc4[rt] = z; }
      #pragma unroll
      for (int ks=0; ks<4; ks++){
        uint32_t abyte = (uint32_t)(ks*64 + q*16);
        v8h b = *(const v8h*)(sm + W4_OFF + swz256((uint32_t)r, abyte));
        #pragma unroll
        for (int rt=0;rt<4;rt++){
          v8h a = *(const v8h*)(sm + H_OFF + swz256((uint32_t)(wrow0 + rt*16 + r), abyte));
          acc4[rt] = __builtin_amdgcn_mfma_f32_16x16x32_f16(a, b, acc4[rt], 0,0,0);
        }
      }
      if (r < 2){
        float bv = bl[384 + r];
        #pragma unroll
        for (int rt=0;rt<4;rt++){
          #pragma unroll
          for (int j=0;j<4;j++){
            uint32_t row = (uint32_t)(wrow0 + rt*16 + q*4 + j);
            *(float*)(sm + H_OFF + swz256(row, (uint32_t)(r*4))) = acc4[rt][j] + bv;
          }
        }
      }
    }
    __syncthreads();

    // readout: thread = row, contiguous float2 (cols 0,1 share a 16B swizzle block)
    {
      int grow = r0 + tid;
      if (grow < N){
        float2 v = *(const float2*)(sm + H_OFF + swz256((uint32_t)tid, 0u));
        ((float2*)out)[grow] = v;
      }
    }
  }
}

// ============================ fused fallback (verified round 1) ============================
__global__ __launch_bounds__(NTHR, 2)
void ngp_fused(const float* __restrict__ x,
               const float* __restrict__ table,
               const float* __restrict__ W1, const float* __restrict__ b1,
               const float* __restrict__ W2, const float* __restrict__ b2,
               const float* __restrict__ W3, const float* __restrict__ b3,
               const float* __restrict__ W4, const float* __restrict__ b4,
               float* __restrict__ out, int N)
{
  extern __shared__ char sm[];
  const int tid  = (int)threadIdx.x;
  const int lane = tid & 63;
  const int wave = tid >> 6;

  for (int i = tid; i < 128*32; i += NTHR){
    uint32_t o = (uint32_t)(i >> 5), k = (uint32_t)(i & 31);
    *(_Float16*)(sm + W1_OFF + swz64(o, k*2u)) = (_Float16)W1[i];
  }
  for (int i = tid; i < 128*128; i += NTHR){
    uint32_t o = (uint32_t)(i >> 7), k = (uint32_t)(i & 127);
    *(_Float16*)(sm + W2_OFF + swz256(o, k*2u)) = (_Float16)W2[i];
    *(_Float16*)(sm + W3_OFF + swz256(o, k*2u)) = (_Float16)W3[i];
  }
  for (int i = tid; i < 2*128; i += NTHR){
    uint32_t o = (uint32_t)(i >> 7), k = (uint32_t)(i & 127);
    *(_Float16*)(sm + W4_OFF + swz256(o, k*2u)) = (_Float16)W4[i];
  }
  {
    float* bl = (float*)(sm + B_OFF);
    for (int i = tid; i < 128; i += NTHR){ bl[i] = b1[i]; bl[128+i] = b2[i]; bl[256+i] = b3[i]; }
    if (tid < 2) bl[384+tid] = b4[tid];
  }

  const int ntiles = (N + BM - 1) / BM;
  for (int tile = (int)blockIdx.x; tile < ntiles; tile += (int)gridDim.x){
    const int r0 = tile * BM;
    __syncthreads();

    #pragma unroll
    for (int t=0;t<4;t++){
      int task = t*NTHR + tid;
      int row  = task >> 3;
      int lev  = task & 7;
      int grow = r0 + row;
      if (grow < N){
        float px = x[grow*6+0], py = x[grow*6+1], pz = x[grow*6+2];
        float res = (float)(16 << lev);
        px *= res; py *= res; pz *= res;
        float fx = floorf(px), fy = floorf(py), fz = floorf(pz);
        float rx = px-fx, ry = py-fy, rz = pz-fz;
        uint32_t ix=(uint32_t)fx, iy=(uint32_t)fy, iz=(uint32_t)fz;
        uint32_t hx0=ix,      hx1=ix+1u;
        uint32_t hy0=iy*P2c,  hy1=(iy+1u)*P2c;
        uint32_t hz0=iz*P3c,  hz1=(iz+1u)*P3c;
        const float2* tbl = (const float2*)table + (size_t)lev*TSIZE;
        const uint32_t m = TSIZE-1u;
        float2 f0 = tbl[(hx0^hy0^hz0)&m];
        float2 f1 = tbl[(hx1^hy0^hz0)&m];
        float2 f2 = tbl[(hx0^hy1^hz0)&m];
        float2 f3 = tbl[(hx1^hy1^hz0)&m];
        float2 f4 = tbl[(hx0^hy0^hz1)&m];
        float2 f5 = tbl[(hx1^hy0^hz1)&m];
        float2 f6 = tbl[(hx0^hy1^hz1)&m];
        float2 f7 = tbl[(hx1^hy1^hz1)&m];
        float wx0=1.f-rx, wy0=1.f-ry, wz0=1.f-rz;
        float w0=wx0*wy0*wz0, w1=rx*wy0*wz0, w2=wx0*ry*wz0, w3=rx*ry*wz0;
        float w4=wx0*wy0*rz,  w5=rx*wy0*rz,  w6=wx0*ry*rz,  w7=rx*ry*rz;
        float s0 = f0.x*w0+f1.x*w1+f2.x*w2+f3.x*w3+f4.x*w4+f5.x*w5+f6.x*w6+f7.x*w7;
        float s1 = f0.y*w0+f1.y*w1+f2.y*w2+f3.y*w3+f4.y*w4+f5.y*w5+f6.y*w6+f7.y*w7;
        union { _Float16 h[2]; uint32_t u; } p;
        p.h[0]=(_Float16)s0; p.h[1]=(_Float16)s1;
        *(uint32_t*)(sm + H_OFF + swz256((uint32_t)row, (uint32_t)(lev*4))) = p.u;
      }
    }
    if (tid < BM){
      int row = tid, grow = r0 + row;
      if (grow < N) sh_to_lds(sm, x, grow, (uint32_t)row);
    }
    __syncthreads();

    const int wrow0 = wave * 32;
    const float* bl = (const float*)(sm + B_OFF);
    mlp_layer<32, 128, 2, true>(sm, W1_OFF, bl,       wrow0, lane);
    mlp_layer<128,128, 2, true>(sm, W2_OFF, bl + 128, wrow0, lane);
    mlp_layer<128,128, 2, true>(sm, W3_OFF, bl + 256, wrow0, lane);
    {
      const int r = lane & 15, q = lane >> 4;
      v4f acc0 = {0.f,0.f,0.f,0.f}, acc1 = {0.f,0.f,0.f,0.f};
      #pragma unroll
      for (int ks=0; ks<4; ks++){
        uint32_t abyte = (uint32_t)(ks*64 + q*16);
        v8h a0 = *(const v8h*)(sm + H_OFF + swz256((uint32_t)(wrow0 + r),      abyte));
        v8h a1 = *(const v8h*)(sm + H_OFF + swz256((uint32_t)(wrow0 + 16 + r), abyte));
        v8h b  = *(const v8h*)(sm + W4_OFF + swz256((uint32_t)r, abyte));
        acc0 = __builtin_amdgcn_mfma_f32_16x16x32_f16(a0, b, acc0, 0,0,0);
        acc1 = __builtin_amdgcn_mfma_f32_16x16x32_f16(a1, b, acc1, 0,0,0);
      }
      if (r < 2){
        float bv = bl[384 + r];
        #pragma unroll
        for (int j=0;j<4;j++){
          uint32_t row0 = (uint32_t)(wrow0 + q*4 + j);
          *(float*)(sm + H_OFF + swz256(row0,       (uint32_t)(r*4))) = acc0[j] + bv;
          *(float*)(sm + H_OFF + swz256(row0 + 16u, (uint32_t)(r*4))) = acc1[j] + bv;
        }
      }
    }
    __syncthreads();

    {
      int row = tid >> 1, col = tid & 1;
      int grow = r0 + row;
      if (grow < N){
        out[grow*2 + col] = *(const float*)(sm + H_OFF + swz256((uint32_t)row, (uint32_t)(col*4)));
      }
    }
  }
}

extern "C" void kernel_launch(void* const* d_in, const int* in_sizes, int n_in,
                              void* d_out, int out_size, void* d_ws, size_t ws_size,
                              hipStream_t stream)
{
  const float* x  = (const float*)d_in[0];
  const float* tb = (const float*)d_in[1];
  const float* W1 = (const float*)d_in[2];
  const float* b1 = (const float*)d_in[3];
  const float* W2 = (const float*)d_in[4];
  const float* b2 = (const float*)d_in[5];
  const float* W3 = (const float*)d_in[6];
  const float* b3 = (const float*)d_in[7];
  const float* W4 = (const float*)d_in[8];
  const float* b4 = (const float*)d_in[9];
  float* out = (float*)d_out;
  const int N = in_sizes[0] / 6;

  const size_t tbl16_bytes  = (size_t)8 * TSIZE * 2 * sizeof(_Float16);   // 16 MB
  const size_t planes_bytes = (size_t)8 * (size_t)N * 4u;                 // 32 MB
  const size_t need = tbl16_bytes + planes_bytes;

  if (ws_size >= need){
    _Float16* tbl16 = (_Float16*)d_ws;
    uint32_t* planes = (uint32_t*)((char*)d_ws + tbl16_bytes);

    (void)hipFuncSetAttribute((const void*)mlp_kernel,
                              hipFuncAttributeMaxDynamicSharedMemorySize, (int)LDS_BYTES);

    cvt_table<<<2048, 256, 0, stream>>>(tb, tbl16, (int)(8u*TSIZE*2u/4u));
    encode<<<4096, 256, 0, stream>>>(x, tbl16, planes, N);

    const int ntiles = (N + BM - 1) / BM;
    const int grid = ntiles < 1024 ? ntiles : 1024;
    mlp_kernel<<<grid, NT2, LDS_BYTES, stream>>>(x, planes, W1, b1, W2, b2, W3, b3, W4, b4, out, N);
  } else {
    (void)hipFuncSetAttribute((const void*)ngp_fused,
                              hipFuncAttributeMaxDynamicSharedMemorySize, (int)LDS_BYTES);
    const int ntiles = (N + BM - 1) / BM;
    const int grid = ntiles < 1024 ? ntiles : 1024;
    ngp_fused<<<grid, NTHR, LDS_BYTES, stream>>>(x, tb, W1, b1, W2, b2, W3, b3, W4, b4, out, N);
  }
}